// Round 11
// baseline (544.290 us; speedup 1.0000x reference)
//
#include <hip/hip_runtime.h>
#include <hip/hip_bf16.h>

#define D_ 1024
#define T_ 2048
#define B_ 4
#define H_ 16
#define HS_ 64
#define DFF_ 4096
#define M_TOT 8192  // B*T

typedef short s8v __attribute__((ext_vector_type(8)));
typedef float f4v __attribute__((ext_vector_type(4)));

__device__ __forceinline__ void gll16(const void* g, void* l) {
  __builtin_amdgcn_global_load_lds(
      (__attribute__((address_space(1))) void*)(g),
      (__attribute__((address_space(3))) void*)(l), 16, 0, 0);
}

__device__ __forceinline__ short f2b(float f) {
  __hip_bfloat16 h = __float2bfloat16(f);
  short s; __builtin_memcpy(&s, &h, 2); return s;
}

#define VMCNT(N) asm volatile("s_waitcnt vmcnt(" #N ")" ::: "memory")
#define SBAR()  do { __builtin_amdgcn_s_barrier(); __builtin_amdgcn_sched_barrier(0); } while (0)

// ---------------- fused weight transpose+cast: 6 jobs in one launch.
__global__ __launch_bounds__(256) void transpose_all_kernel(
    const float* __restrict__ wq, const float* __restrict__ wk,
    const float* __restrict__ wv, const float* __restrict__ wo,
    const float* __restrict__ w1, const float* __restrict__ w2,
    __hip_bfloat16* __restrict__ qkvT, __hip_bfloat16* __restrict__ woT,
    __hip_bfloat16* __restrict__ w1T, __hip_bfloat16* __restrict__ w2T) {
  const int bid = blockIdx.x;
  const float* src; __hip_bfloat16* dst;
  int R, C, rb, bx, by;
  if (bid < 3072) {        // wq/wk/wv: (1024,64) per head-slice
    int j = bid >> 10, w = bid & 1023;
    src = (j == 0) ? wq : (j == 1) ? wk : wv;
    dst = qkvT; R = 1024; C = 64;
    int z = w >> 6, xy = w & 63;
    bx = xy & 1; by = xy >> 1;
    src += (size_t)z * R * C;
    rb = j * 1024 + z * C;
  } else if (bid < 4096) { // wo: (1024,1024)
    int w = bid - 3072;
    src = wo; dst = woT; R = 1024; C = 1024; rb = 0;
    bx = w & 31; by = w >> 5;
  } else if (bid < 8192) { // w1: (1024,4096)
    int w = bid - 4096;
    src = w1; dst = w1T; R = 1024; C = 4096; rb = 0;
    bx = w & 127; by = w >> 7;
  } else {                 // w2: (4096,1024)
    int w = bid - 8192;
    src = w2; dst = w2T; R = 4096; C = 1024; rb = 0;
    bx = w & 31; by = w >> 5;
  }
  __shared__ float tile[32][33];
  int c0 = bx * 32, r0 = by * 32;
  int tx = threadIdx.x, ty = threadIdx.y;  // (32, 8)
#pragma unroll
  for (int i = 0; i < 4; ++i)
    tile[ty + i * 8][tx] = src[(size_t)(r0 + ty + i * 8) * C + c0 + tx];
  __syncthreads();
#pragma unroll
  for (int i = 0; i < 4; ++i)
    dst[(size_t)(rb + c0 + ty + i * 8) * R + r0 + tx] =
        __float2bfloat16(tile[tx][ty + i * 8]);
}

// ---------------- V transpose per head: (b,h,T,HS) -> (b,h,HS,T), bf16
__global__ __launch_bounds__(256) void transpose_v_kernel(
    const __hip_bfloat16* __restrict__ Vb, __hip_bfloat16* __restrict__ Vt) {
  const int bh = blockIdx.y;
  const int t0 = blockIdx.x * 64;
  __shared__ short tile[64][72];
  const int tid = threadIdx.x;
  const int r = tid >> 2, cg = tid & 3;
  const __hip_bfloat16* src = Vb + ((size_t)bh * T_ + t0 + r) * HS_ + cg * 16;
  s8v v0 = *(const s8v*)(src);
  s8v v1 = *(const s8v*)(src + 8);
  *(s8v*)&tile[r][cg * 16] = v0;
  *(s8v*)&tile[r][cg * 16 + 8] = v1;
  __syncthreads();
  const int hs = r;
  short o0[8], o1[8];
#pragma unroll
  for (int k2 = 0; k2 < 8; ++k2) o0[k2] = tile[cg * 16 + k2][hs];
#pragma unroll
  for (int k2 = 0; k2 < 8; ++k2) o1[k2] = tile[cg * 16 + 8 + k2][hs];
  __hip_bfloat16* dst = Vt + ((size_t)bh * HS_ + hs) * T_ + t0 + cg * 16;
  *(s8v*)dst = *(s8v*)o0;
  *(s8v*)(dst + 8) = *(s8v*)o1;
}

// ---------------- LayerNorm: fp32 row (1024) -> bf16 row
__global__ __launch_bounds__(256) void ln_kernel(
    const float* __restrict__ x, const float* __restrict__ g,
    const float* __restrict__ be, __hip_bfloat16* __restrict__ out) {
  int row = blockIdx.x;
  int t = threadIdx.x;
  float4 v = ((const float4*)(x + (size_t)row * D_))[t];
  float s = v.x + v.y + v.z + v.w;
  float ss = v.x * v.x + v.y * v.y + v.z * v.z + v.w * v.w;
#pragma unroll
  for (int o = 1; o < 64; o <<= 1) { s += __shfl_xor(s, o); ss += __shfl_xor(ss, o); }
  __shared__ float rs[4], rss[4];
  int w = t >> 6, l = t & 63;
  if (l == 0) { rs[w] = s; rss[w] = ss; }
  __syncthreads();
  s = rs[0] + rs[1] + rs[2] + rs[3];
  ss = rss[0] + rss[1] + rss[2] + rss[3];
  float mu = s * (1.f / D_);
  float var = ss * (1.f / D_) - mu * mu;
  float r = rsqrtf(var + 1e-5f);
  float4 gv = ((const float4*)g)[t];
  float4 bv = ((const float4*)be)[t];
  union { ushort4 u; __hip_bfloat16 h[4]; } pk;
  pk.h[0] = __float2bfloat16((v.x - mu) * r * gv.x + bv.x);
  pk.h[1] = __float2bfloat16((v.y - mu) * r * gv.y + bv.y);
  pk.h[2] = __float2bfloat16((v.z - mu) * r * gv.z + bv.z);
  pk.h[3] = __float2bfloat16((v.w - mu) * r * gv.w + bv.w);
  ((ushort4*)(out + (size_t)row * D_))[t] = pk.u;
}

// ---------------- 128^2 GEMM (EPI1: p0 fp32 = res + C + bias), counted-vmcnt
// schedule: phases -> raw bar -> restage kt+2 into dead buf -> vmcnt(4) -> bar.
// LDS swizzle slot^=(row>>1)&3 on 16B slots of 64B rows (2-way = free).
__global__ __launch_bounds__(256) void gemm_bt_kernel(
    const __hip_bfloat16* __restrict__ A, const __hip_bfloat16* __restrict__ Bt,
    int M, int N, int K,
    float* __restrict__ p0, const float* __restrict__ bias,
    const float* __restrict__ res) {
  __shared__ short sA[2][128 * 32], sB[2][128 * 32];
  const int gdx = gridDim.x;
  const int nwg = gdx * gridDim.y;
  const int orig = blockIdx.y * gdx + blockIdx.x;
  const int xcd = orig & 7;
  const int c = orig >> 3;
  const int rows = (nwg >> 3) / gdx;
  const int i2 = c & 1;
  const int nn = (c >> 1) % gdx;
  const int gg = (c >> 1) / gdx;
  const int m0 = (xcd * rows + gg * 2 + i2) * 128, n0 = nn * 128;
  const int t = threadIdx.x, l = t & 63, w = t >> 6;
  const int wr = w >> 1, wc = w & 1, lg = l >> 4, lo = l & 15;
  f4v acc[4][4];
#pragma unroll
  for (int m = 0; m < 4; ++m)
#pragma unroll
    for (int n = 0; n < 4; ++n) acc[m][n] = (f4v){0.f, 0.f, 0.f, 0.f};
  const int NT = K >> 5;
  auto stage = [&](int kt, int bi) {
#pragma unroll
    for (int j = 0; j < 2; ++j) {
      int i = j * 256 + t;
      int row = i >> 2, sl = i & 3;
      int ss = sl ^ ((row >> 1) & 3);
      gll16(A + (size_t)(m0 + row) * K + kt * 32 + ss * 8, (char*)sA[bi] + i * 16);
      gll16(Bt + (size_t)(n0 + row) * K + kt * 32 + ss * 8, (char*)sB[bi] + i * 16);
    }
  };
  stage(0, 0);
  stage(1, 1);
  VMCNT(4);
  SBAR();
  for (int kt = 0; kt < NT; ++kt) {
    const int bi = kt & 1;
    s8v af[4], bf[4];
#pragma unroll
    for (int m = 0; m < 4; ++m) {
      int row = wr * 64 + m * 16 + lo;
      int ss = lg ^ ((row >> 1) & 3);
      af[m] = *(const s8v*)((const char*)sA[bi] + row * 64 + ss * 16);
    }
#pragma unroll
    for (int n = 0; n < 4; ++n) {
      int row = wc * 64 + n * 16 + lo;
      int ss = lg ^ ((row >> 1) & 3);
      bf[n] = *(const s8v*)((const char*)sB[bi] + row * 64 + ss * 16);
    }
    __builtin_amdgcn_s_setprio(1);
#pragma unroll
    for (int m = 0; m < 4; ++m)
#pragma unroll
      for (int n = 0; n < 4; ++n)
        acc[m][n] = __builtin_amdgcn_mfma_f32_16x16x32_bf16(af[m], bf[n], acc[m][n], 0, 0, 0);
    __builtin_amdgcn_s_setprio(0);
    if (kt == NT - 1) break;
    SBAR();  // all waves done reading buf bi
    if (kt + 2 < NT) { stage(kt + 2, bi); VMCNT(4); }  // kt+1 landed; kt+2 flies
    else             { VMCNT(0); }
    SBAR();  // buf bi^1 globally ready
  }
  // epilogue
#pragma unroll
  for (int mi = 0; mi < 4; ++mi)
#pragma unroll
    for (int j = 0; j < 4; ++j) {
      int mg = m0 + wr * 64 + mi * 16 + lg * 4 + j;
#pragma unroll
      for (int ni = 0; ni < 4; ++ni) {
        int ng = n0 + wc * 64 + ni * 16 + lo;
        p0[(size_t)mg * N + ng] = res[(size_t)mg * N + ng] + acc[mi][ni][j] + bias[ng];
      }
    }
}

// ---------------- 256^2 GEMM, BK=32, 8 waves (2M x 4N), counted-vmcnt schedule.
// LDS 64KB static (2 dbuf x (256x32 A + 256x32 B) bf16), swizzled as above.
// EPI 0: scatter to Q,K,V bf16 (p0,p1,p2);  EPI 2: p0 bf16 = relu(C + bias)
template <int EPI>
__global__ __launch_bounds__(512, 2) void gemm_bt_256(
    const __hip_bfloat16* __restrict__ A, const __hip_bfloat16* __restrict__ Bt,
    int M, int N, int K,
    void* __restrict__ p0, void* __restrict__ p1, void* __restrict__ p2,
    const float* __restrict__ bias) {
  __shared__ short sA[2][256 * 32], sB[2][256 * 32];
  const int gdx = gridDim.x;           // N/256
  const int gdy = gridDim.y;           // M/256 (multiple of 8)
  const int orig = blockIdx.y * gdx + blockIdx.x;
  const int xcd = orig & 7;
  const int c = orig >> 3;
  const int rowsPerXcd = gdy >> 3;
  const int g = c / (2 * gdx);         // m-pair index within XCD chunk
  const int r = c % (2 * gdx);
  const int i2 = r & 1, nn = r >> 1;   // n-fastest: A-pair stays L2-resident
  const int m0 = (xcd * rowsPerXcd + g * 2 + i2) * 256;
  const int n0 = nn * 256;
  const int t = threadIdx.x, l = t & 63, wid = t >> 6;
  const int wm = wid >> 2, wn = wid & 3, lg = l >> 4, lo = l & 15;
  f4v acc[8][4];
#pragma unroll
  for (int m = 0; m < 8; ++m)
#pragma unroll
    for (int n = 0; n < 4; ++n) acc[m][n] = (f4v){0.f, 0.f, 0.f, 0.f};
  const int NT = K >> 5;
  auto stage = [&](int kt, int bi) {
#pragma unroll
    for (int j = 0; j < 2; ++j) {
      int i = j * 512 + t;
      int row = i >> 2, sl = i & 3;
      int ss = sl ^ ((row >> 1) & 3);
      gll16(A + (size_t)(m0 + row) * K + kt * 32 + ss * 8, (char*)sA[bi] + i * 16);
      gll16(Bt + (size_t)(n0 + row) * K + kt * 32 + ss * 8, (char*)sB[bi] + i * 16);
    }
  };
  stage(0, 0);
  stage(1, 1);
  VMCNT(4);
  SBAR();
  for (int kt = 0; kt < NT; ++kt) {
    const int bi = kt & 1;
    const char* cA = (const char*)sA[bi];
    const char* cB = (const char*)sB[bi];
    s8v bf[4];
#pragma unroll
    for (int nr = 0; nr < 4; ++nr) {
      int row = wn * 64 + nr * 16 + lo;
      int ss = lg ^ ((row >> 1) & 3);
      bf[nr] = *(const s8v*)(cB + row * 64 + ss * 16);
    }
    // phase 0: m-reps 0-3
    {
      s8v af[4];
#pragma unroll
      for (int mr = 0; mr < 4; ++mr) {
        int row = wm * 128 + mr * 16 + lo;
        int ss = lg ^ ((row >> 1) & 3);
        af[mr] = *(const s8v*)(cA + row * 64 + ss * 16);
      }
      __builtin_amdgcn_s_setprio(1);
#pragma unroll
      for (int mr = 0; mr < 4; ++mr)
#pragma unroll
        for (int nr = 0; nr < 4; ++nr)
          acc[mr][nr] = __builtin_amdgcn_mfma_f32_16x16x32_bf16(af[mr], bf[nr], acc[mr][nr], 0, 0, 0);
      __builtin_amdgcn_s_setprio(0);
    }
    // phase 1: m-reps 4-7
    {
      s8v af[4];
#pragma unroll
      for (int mr = 0; mr < 4; ++mr) {
        int row = wm * 128 + (mr + 4) * 16 + lo;
        int ss = lg ^ ((row >> 1) & 3);
        af[mr] = *(const s8v*)(cA + row * 64 + ss * 16);
      }
      __builtin_amdgcn_s_setprio(1);
#pragma unroll
      for (int mr = 0; mr < 4; ++mr)
#pragma unroll
        for (int nr = 0; nr < 4; ++nr)
          acc[mr + 4][nr] = __builtin_amdgcn_mfma_f32_16x16x32_bf16(af[mr], bf[nr], acc[mr + 4][nr], 0, 0, 0);
      __builtin_amdgcn_s_setprio(0);
    }
    if (kt == NT - 1) break;
    SBAR();  // all waves done reading buf bi
    if (kt + 2 < NT) { stage(kt + 2, bi); VMCNT(4); }  // kt+1 landed; kt+2 flies
    else             { VMCNT(0); }
    SBAR();  // buf bi^1 globally ready
  }
  // epilogue
#pragma unroll
  for (int mi = 0; mi < 8; ++mi)
#pragma unroll
    for (int j = 0; j < 4; ++j) {
      int mg = m0 + wm * 128 + mi * 16 + lg * 4 + j;
#pragma unroll
      for (int ni = 0; ni < 4; ++ni) {
        int ng = n0 + wn * 64 + ni * 16 + lo;
        float v = acc[mi][ni][j];
        if constexpr (EPI == 0) {
          int wi = ng >> 10, within = ng & 1023, hh = within >> 6, hs = within & 63;
          __hip_bfloat16* dst = (wi == 0) ? (__hip_bfloat16*)p0
                               : (wi == 1) ? (__hip_bfloat16*)p1
                                           : (__hip_bfloat16*)p2;
          int b = mg >> 11, tt = mg & 2047;
          dst[(((size_t)(b * H_ + hh)) * T_ + tt) * HS_ + hs] = __float2bfloat16(v);
        } else {
          float y = v + bias[ng];
          y = y > 0.f ? y : 0.f;
          ((__hip_bfloat16*)p0)[(size_t)mg * N + ng] = __float2bfloat16(y);
        }
      }
    }
}

// ---------------- causal flash attention (round-8 state: max-free softmax,
// KVBLK=64, paired q-tiles, XOR-swizzled LDS, gll16 staging)
template <bool MASK>
__device__ __forceinline__ void attn_step(
    int s0, int qrow, int lg, int lo,
    const short* __restrict__ sKb, const short* __restrict__ sVb,
    short* __restrict__ sPw,
    const s8v (&qf)[2][2], f4v (&acc)[2][4], float (&rsum)[2][4]) {
  s8v kf[4][2];
#pragma unroll
  for (int si = 0; si < 4; ++si) {
    int row = si * 16 + lo;
#pragma unroll
    for (int kc = 0; kc < 2; ++kc) {
      int slot = (kc * 4 + lg) ^ (row & 7);
      kf[si][kc] = *(const s8v*)((const char*)sKb + row * 128 + slot * 16);
    }
  }
  f4v sfr[2][4];
#pragma unroll
  for (int mi = 0; mi < 2; ++mi)
#pragma unroll
    for (int si = 0; si < 4; ++si) {
      sfr[mi][si] = (f4v){0.f, 0.f, 0.f, 0.f};
#pragma unroll
      for (int kc = 0; kc < 2; ++kc)
        sfr[mi][si] = __builtin_amdgcn_mfma_f32_16x16x32_bf16(
            qf[mi][kc], kf[si][kc], sfr[mi][si], 0, 0, 0);
    }
  const float c = 0.18033688f;  // 0.125 * log2(e)
  float p[2][4][4];
#pragma unroll
  for (int mi = 0; mi < 2; ++mi)
#pragma unroll
    for (int si = 0; si < 4; ++si)
#pragma unroll
      for (int j = 0; j < 4; ++j) {
        float vv = sfr[mi][si][j] * c;
        if (MASK) {
          int r = qrow + mi * 16 + lg * 4 + j;
          int s = s0 + si * 16 + lo;
          vv = (s <= r) ? vv : -3e38f;
        }
        float e = exp2f(vv);
        p[mi][si][j] = e;
        rsum[mi][j] += e;
      }
#pragma unroll
  for (int mi = 0; mi < 2; ++mi)
#pragma unroll
    for (int si = 0; si < 4; ++si)
#pragma unroll
      for (int j = 0; j < 4; ++j) {
        int row = mi * 16 + lg * 4 + j;
        int s = si * 16 + lo;
        int slot = (s >> 3) ^ (row & 7);
        *(short*)((char*)sPw + row * 128 + slot * 16 + (s & 7) * 2) =
            f2b(p[mi][si][j]);
      }
  s8v pa[2][2], vf[4][2];
#pragma unroll
  for (int mi = 0; mi < 2; ++mi) {
    int row = mi * 16 + lo;
#pragma unroll
    for (int sb = 0; sb < 2; ++sb) {
      int slot = (sb * 4 + lg) ^ (row & 7);
      pa[mi][sb] = *(const s8v*)((const char*)sPw + row * 128 + slot * 16);
    }
  }
#pragma unroll
  for (int ni = 0; ni < 4; ++ni) {
    int row = ni * 16 + lo;
#pragma unroll
    for (int sb = 0; sb < 2; ++sb) {
      int slot = (sb * 4 + lg) ^ (row & 7);
      vf[ni][sb] = *(const s8v*)((const char*)sVb + row * 128 + slot * 16);
    }
  }
#pragma unroll
  for (int mi = 0; mi < 2; ++mi)
#pragma unroll
    for (int ni = 0; ni < 4; ++ni)
#pragma unroll
      for (int sb = 0; sb < 2; ++sb)
        acc[mi][ni] = __builtin_amdgcn_mfma_f32_16x16x32_bf16(
            pa[mi][sb], vf[ni][sb], acc[mi][ni], 0, 0, 0);
}

__global__ __launch_bounds__(256) void attn_kernel(
    const __hip_bfloat16* __restrict__ Q, const __hip_bfloat16* __restrict__ K,
    const __hip_bfloat16* __restrict__ Vt, __hip_bfloat16* __restrict__ O) {
  const int bh = blockIdx.y;
  const int t = threadIdx.x, w = t >> 6, l = t & 63, lg = l >> 4, lo = l & 15;
  const size_t kbase = (size_t)bh * T_ * HS_;
  const size_t vbase = (size_t)bh * HS_ * T_;
  __shared__ short sK[2][64 * 64];
  __shared__ short sV[2][64 * 64];
  __shared__ short sP[4][32 * 64];
  const int b = bh >> 4, hh = bh & 15;
  for (int pass = 0; pass < 2; ++pass) {
    const int tile = pass ? (15 - (int)blockIdx.x) : (int)blockIdx.x;
    const int q0 = tile * 128;
    const int qrow = q0 + w * 32;
    s8v qf[2][2];
#pragma unroll
    for (int mi = 0; mi < 2; ++mi)
#pragma unroll
      for (int kc = 0; kc < 2; ++kc)
        qf[mi][kc] = *(const s8v*)(Q + kbase +
                                   (size_t)(qrow + mi * 16 + lo) * HS_ +
                                   kc * 32 + lg * 8);
    f4v acc[2][4];
    float rsum[2][4];
#pragma unroll
    for (int mi = 0; mi < 2; ++mi) {
#pragma unroll
      for (int ni = 0; ni < 4; ++ni) acc[mi][ni] = (f4v){0.f, 0.f, 0.f, 0.f};
#pragma unroll
      for (int j = 0; j < 4; ++j) rsum[mi][j] = 0.f;
    }
    const int nst = q0 / 64 + 2;
    auto stg = [&](int st) {
      int bi = st & 1;
      int s0 = st * 64;
#pragma unroll
      for (int r = 0; r < 2; ++r) {
        int i = r * 256 + t;
        int row = i >> 3, sl = i & 7;
        int sls = sl ^ (row & 7);
        gll16(K + kbase + (size_t)(s0 + row) * HS_ + sls * 8,
              (char*)sK[bi] + i * 16);
        gll16(Vt + vbase + (size_t)row * T_ + s0 + sls * 8,
              (char*)sV[bi] + i * 16);
      }
    };
    stg(0);
    __syncthreads();
    for (int st = 0; st < nst; ++st) {
      if (st + 1 < nst) stg(st + 1);
      const int s0 = st * 64;
      if (s0 <= qrow + 31) {
        if (st < nst - 2)
          attn_step<false>(s0, qrow, lg, lo, sK[st & 1], sV[st & 1], sP[w],
                           qf, acc, rsum);
        else
          attn_step<true>(s0, qrow, lg, lo, sK[st & 1], sV[st & 1], sP[w],
                          qf, acc, rsum);
      }
      __syncthreads();
    }
#pragma unroll
    for (int mi = 0; mi < 2; ++mi)
#pragma unroll
      for (int j = 0; j < 4; ++j) {
        float rs = rsum[mi][j];
#pragma unroll
        for (int o = 1; o < 16; o <<= 1) rs += __shfl_xor(rs, o);
        int r = qrow + mi * 16 + lg * 4 + j;
        float inv = 1.f / rs;
#pragma unroll
        for (int ni = 0; ni < 4; ++ni) {
          int cc = ni * 16 + lo;
          O[((size_t)b * T_ + r) * D_ + hh * HS_ + cc] =
              __float2bfloat16(acc[mi][ni][j] * inv);
        }
      }
  }
}

extern "C" void kernel_launch(void* const* d_in, const int* in_sizes, int n_in,
                              void* d_out, int out_size, void* d_ws, size_t ws_size,
                              hipStream_t stream) {
  const float* x   = (const float*)d_in[0];
  const float* wq  = (const float*)d_in[1];
  const float* wk  = (const float*)d_in[2];
  const float* wv  = (const float*)d_in[3];
  const float* wo  = (const float*)d_in[4];
  const float* bo  = (const float*)d_in[5];
  const float* w1  = (const float*)d_in[6];
  const float* b1  = (const float*)d_in[7];
  const float* w2  = (const float*)d_in[8];
  const float* b2  = (const float*)d_in[9];
  const float* g1  = (const float*)d_in[10];
  const float* be1 = (const float*)d_in[11];
  const float* g2  = (const float*)d_in[12];
  const float* be2 = (const float*)d_in[13];
  float* out = (float*)d_out;

  char* ws = (char*)d_ws;
  auto alloc = [&](size_t bytes) {
    char* p = ws;
    ws += (bytes + 255) & ~(size_t)255;
    return p;
  };
  __hip_bfloat16* qkvT  = (__hip_bfloat16*)alloc((size_t)3 * D_ * D_ * 2);
  __hip_bfloat16* woT   = (__hip_bfloat16*)alloc((size_t)D_ * D_ * 2);
  __hip_bfloat16* w1T   = (__hip_bfloat16*)alloc((size_t)DFF_ * D_ * 2);
  __hip_bfloat16* w2T   = (__hip_bfloat16*)alloc((size_t)D_ * DFF_ * 2);
  __hip_bfloat16* hbuf  = (__hip_bfloat16*)alloc((size_t)M_TOT * D_ * 2);
  float*          x1    = (float*)alloc((size_t)M_TOT * D_ * 4);
  __hip_bfloat16* Vtb   = (__hip_bfloat16*)x1;   // disjoint live ranges
  char* aliased = alloc((size_t)M_TOT * DFF_ * 2);
  __hip_bfloat16* Qb    = (__hip_bfloat16*)(aliased);
  __hip_bfloat16* Kb    = (__hip_bfloat16*)(aliased + (size_t)M_TOT * D_ * 2);
  __hip_bfloat16* Vb    = (__hip_bfloat16*)(aliased + (size_t)M_TOT * D_ * 4);
  __hip_bfloat16* attnb = (__hip_bfloat16*)(aliased + (size_t)M_TOT * D_ * 6);
  __hip_bfloat16* ffb   = (__hip_bfloat16*)(aliased);

  transpose_all_kernel<<<dim3(12288), dim3(32, 8), 0, stream>>>(
      wq, wk, wv, wo, w1, w2, qkvT, woT, w1T, w2T);
  ln_kernel<<<M_TOT, 256, 0, stream>>>(x, g1, be1, hbuf);
  // QKV (256^2)
  gemm_bt_256<0><<<dim3(12, 32), 512, 0, stream>>>(hbuf, qkvT, M_TOT, 3 * D_, D_,
                                                   Qb, Kb, Vb, nullptr);
  transpose_v_kernel<<<dim3(32, 64), 256, 0, stream>>>(Vb, Vtb);
  attn_kernel<<<dim3(8, 64), 256, 0, stream>>>(Qb, Kb, Vtb, attnb);
  // out proj + residual (128^2)
  gemm_bt_kernel<<<dim3(8, 64), 256, 0, stream>>>(attnb, woT, M_TOT, D_, D_,
                                                  x1, bo, x);
  ln_kernel<<<M_TOT, 256, 0, stream>>>(x1, g2, be2, hbuf);
  // FFN1 relu (256^2)
  gemm_bt_256<2><<<dim3(16, 32), 512, 0, stream>>>(hbuf, w1T, M_TOT, DFF_, D_,
                                                   ffb, nullptr, nullptr, b1);
  // FFN2 + residual -> out (128^2)
  gemm_bt_kernel<<<dim3(8, 64), 256, 0, stream>>>(ffb, w2T, M_TOT, D_, DFF_,
                                                  out, b2, x1);
}

// Round 12
// 498.189 us; speedup vs baseline: 1.0925x; 1.0925x over previous
//
#include <hip/hip_runtime.h>
#include <hip/hip_bf16.h>

#define D_ 1024
#define T_ 2048
#define B_ 4
#define H_ 16
#define HS_ 64
#define DFF_ 4096
#define M_TOT 8192  // B*T

typedef short s8v __attribute__((ext_vector_type(8)));
typedef float f4v __attribute__((ext_vector_type(4)));

__device__ __forceinline__ void gll16(const void* g, void* l) {
  __builtin_amdgcn_global_load_lds(
      (__attribute__((address_space(1))) void*)(g),
      (__attribute__((address_space(3))) void*)(l), 16, 0, 0);
}

__device__ __forceinline__ short f2b(float f) {
  __hip_bfloat16 h = __float2bfloat16(f);
  short s; __builtin_memcpy(&s, &h, 2); return s;
}

#define VMCNT(N) asm volatile("s_waitcnt vmcnt(" #N ")" ::: "memory")
#define BAR() do { __builtin_amdgcn_s_barrier(); asm volatile("" ::: "memory"); } while (0)

// ---------------- fused weight transpose+cast: 6 jobs in one launch.
__global__ __launch_bounds__(256) void transpose_all_kernel(
    const float* __restrict__ wq, const float* __restrict__ wk,
    const float* __restrict__ wv, const float* __restrict__ wo,
    const float* __restrict__ w1, const float* __restrict__ w2,
    __hip_bfloat16* __restrict__ qkvT, __hip_bfloat16* __restrict__ woT,
    __hip_bfloat16* __restrict__ w1T, __hip_bfloat16* __restrict__ w2T) {
  const int bid = blockIdx.x;
  const float* src; __hip_bfloat16* dst;
  int R, C, rb, bx, by;
  if (bid < 3072) {        // wq/wk/wv: (1024,64) per head-slice
    int j = bid >> 10, w = bid & 1023;
    src = (j == 0) ? wq : (j == 1) ? wk : wv;
    dst = qkvT; R = 1024; C = 64;
    int z = w >> 6, xy = w & 63;
    bx = xy & 1; by = xy >> 1;
    src += (size_t)z * R * C;
    rb = j * 1024 + z * C;
  } else if (bid < 4096) { // wo: (1024,1024)
    int w = bid - 3072;
    src = wo; dst = woT; R = 1024; C = 1024; rb = 0;
    bx = w & 31; by = w >> 5;
  } else if (bid < 8192) { // w1: (1024,4096)
    int w = bid - 4096;
    src = w1; dst = w1T; R = 1024; C = 4096; rb = 0;
    bx = w & 127; by = w >> 7;
  } else {                 // w2: (4096,1024)
    int w = bid - 8192;
    src = w2; dst = w2T; R = 4096; C = 1024; rb = 0;
    bx = w & 31; by = w >> 5;
  }
  __shared__ float tile[32][33];
  int c0 = bx * 32, r0 = by * 32;
  int tx = threadIdx.x, ty = threadIdx.y;  // (32, 8)
#pragma unroll
  for (int i = 0; i < 4; ++i)
    tile[ty + i * 8][tx] = src[(size_t)(r0 + ty + i * 8) * C + c0 + tx];
  __syncthreads();
#pragma unroll
  for (int i = 0; i < 4; ++i)
    dst[(size_t)(rb + c0 + ty + i * 8) * R + r0 + tx] =
        __float2bfloat16(tile[tx][ty + i * 8]);
}

// ---------------- V transpose per head: (b,h,T,HS) -> (b,h,HS,T), bf16
__global__ __launch_bounds__(256) void transpose_v_kernel(
    const __hip_bfloat16* __restrict__ Vb, __hip_bfloat16* __restrict__ Vt) {
  const int bh = blockIdx.y;
  const int t0 = blockIdx.x * 64;
  __shared__ short tile[64][72];
  const int tid = threadIdx.x;
  const int r = tid >> 2, cg = tid & 3;
  const __hip_bfloat16* src = Vb + ((size_t)bh * T_ + t0 + r) * HS_ + cg * 16;
  s8v v0 = *(const s8v*)(src);
  s8v v1 = *(const s8v*)(src + 8);
  *(s8v*)&tile[r][cg * 16] = v0;
  *(s8v*)&tile[r][cg * 16 + 8] = v1;
  __syncthreads();
  const int hs = r;
  short o0[8], o1[8];
#pragma unroll
  for (int k2 = 0; k2 < 8; ++k2) o0[k2] = tile[cg * 16 + k2][hs];
#pragma unroll
  for (int k2 = 0; k2 < 8; ++k2) o1[k2] = tile[cg * 16 + 8 + k2][hs];
  __hip_bfloat16* dst = Vt + ((size_t)bh * HS_ + hs) * T_ + t0 + cg * 16;
  *(s8v*)dst = *(s8v*)o0;
  *(s8v*)(dst + 8) = *(s8v*)o1;
}

// ---------------- LayerNorm: fp32 row (1024) -> bf16 row
__global__ __launch_bounds__(256) void ln_kernel(
    const float* __restrict__ x, const float* __restrict__ g,
    const float* __restrict__ be, __hip_bfloat16* __restrict__ out) {
  int row = blockIdx.x;
  int t = threadIdx.x;
  float4 v = ((const float4*)(x + (size_t)row * D_))[t];
  float s = v.x + v.y + v.z + v.w;
  float ss = v.x * v.x + v.y * v.y + v.z * v.z + v.w * v.w;
#pragma unroll
  for (int o = 1; o < 64; o <<= 1) { s += __shfl_xor(s, o); ss += __shfl_xor(ss, o); }
  __shared__ float rs[4], rss[4];
  int w = t >> 6, l = t & 63;
  if (l == 0) { rs[w] = s; rss[w] = ss; }
  __syncthreads();
  s = rs[0] + rs[1] + rs[2] + rs[3];
  ss = rss[0] + rss[1] + rss[2] + rss[3];
  float mu = s * (1.f / D_);
  float var = ss * (1.f / D_) - mu * mu;
  float r = rsqrtf(var + 1e-5f);
  float4 gv = ((const float4*)g)[t];
  float4 bv = ((const float4*)be)[t];
  union { ushort4 u; __hip_bfloat16 h[4]; } pk;
  pk.h[0] = __float2bfloat16((v.x - mu) * r * gv.x + bv.x);
  pk.h[1] = __float2bfloat16((v.y - mu) * r * gv.y + bv.y);
  pk.h[2] = __float2bfloat16((v.z - mu) * r * gv.z + bv.z);
  pk.h[3] = __float2bfloat16((v.w - mu) * r * gv.w + bv.w);
  ((ushort4*)(out + (size_t)row * D_))[t] = pk.u;
}

// ---------------- 128^2 GEMM, triple-buffered counted-vmcnt pipeline.
// Per K-step: VMCNT(4) [retires tile kt, issued 2 iters ago; kt+1 flies]
// -> barrier -> ds_read+MFMA -> stage(kt+2). One barrier/step, no sched fences.
// EPI 0: scatter to Q,K,V bf16 (p0,p1,p2);  EPI 1: p0 fp32 = res + C + bias.
template <int EPI>
__global__ __launch_bounds__(256) void gemm_bt_128(
    const __hip_bfloat16* __restrict__ A, const __hip_bfloat16* __restrict__ Bt,
    int M, int N, int K,
    void* __restrict__ p0, void* __restrict__ p1, void* __restrict__ p2,
    const float* __restrict__ bias, const float* __restrict__ res) {
  __shared__ short sA[3][128 * 32], sB[3][128 * 32];
  const int gdx = gridDim.x;
  const int nwg = gdx * gridDim.y;
  const int orig = blockIdx.y * gdx + blockIdx.x;
  const int xcd = orig & 7;
  const int c = orig >> 3;
  const int rows = (nwg >> 3) / gdx;
  const int i2 = c & 1;
  const int nn = (c >> 1) % gdx;
  const int gg = (c >> 1) / gdx;
  const int m0 = (xcd * rows + gg * 2 + i2) * 128, n0 = nn * 128;
  const int t = threadIdx.x, l = t & 63, w = t >> 6;
  const int wr = w >> 1, wc = w & 1, lg = l >> 4, lo = l & 15;
  f4v acc[4][4];
#pragma unroll
  for (int m = 0; m < 4; ++m)
#pragma unroll
    for (int n = 0; n < 4; ++n) acc[m][n] = (f4v){0.f, 0.f, 0.f, 0.f};
  const int NT = K >> 5;
  auto stage = [&](int kt, int bi) {
#pragma unroll
    for (int j = 0; j < 2; ++j) {
      int i = j * 256 + t;
      int row = i >> 2, sl = i & 3;
      int ss = sl ^ ((row >> 1) & 3);
      gll16(A + (size_t)(m0 + row) * K + kt * 32 + ss * 8, (char*)sA[bi] + i * 16);
      gll16(Bt + (size_t)(n0 + row) * K + kt * 32 + ss * 8, (char*)sB[bi] + i * 16);
    }
  };
  stage(0, 0);
  stage(1, 1);
  int bi = 0, bs = 2;
  for (int kt = 0; kt < NT; ++kt) {
    if (kt + 1 < NT) { VMCNT(4); } else { VMCNT(0); }
    BAR();
    s8v af[4], bf[4];
#pragma unroll
    for (int m = 0; m < 4; ++m) {
      int row = wr * 64 + m * 16 + lo;
      int ss = lg ^ ((row >> 1) & 3);
      af[m] = *(const s8v*)((const char*)sA[bi] + row * 64 + ss * 16);
    }
#pragma unroll
    for (int n = 0; n < 4; ++n) {
      int row = wc * 64 + n * 16 + lo;
      int ss = lg ^ ((row >> 1) & 3);
      bf[n] = *(const s8v*)((const char*)sB[bi] + row * 64 + ss * 16);
    }
    __builtin_amdgcn_s_setprio(1);
#pragma unroll
    for (int m = 0; m < 4; ++m)
#pragma unroll
      for (int n = 0; n < 4; ++n)
        acc[m][n] = __builtin_amdgcn_mfma_f32_16x16x32_bf16(af[m], bf[n], acc[m][n], 0, 0, 0);
    __builtin_amdgcn_s_setprio(0);
    if (kt + 2 < NT) stage(kt + 2, bs);
    bi = (bi == 2) ? 0 : bi + 1;
    bs = (bs == 2) ? 0 : bs + 1;
  }
  // epilogue
#pragma unroll
  for (int mi = 0; mi < 4; ++mi)
#pragma unroll
    for (int j = 0; j < 4; ++j) {
      int mg = m0 + wr * 64 + mi * 16 + lg * 4 + j;
#pragma unroll
      for (int ni = 0; ni < 4; ++ni) {
        int ng = n0 + wc * 64 + ni * 16 + lo;
        float v = acc[mi][ni][j];
        if constexpr (EPI == 0) {
          int wi = ng >> 10, within = ng & 1023, hh = within >> 6, hs = within & 63;
          __hip_bfloat16* dst = (wi == 0) ? (__hip_bfloat16*)p0
                               : (wi == 1) ? (__hip_bfloat16*)p1
                                           : (__hip_bfloat16*)p2;
          int b = mg >> 11, tt = mg & 2047;
          dst[(((size_t)(b * H_ + hh)) * T_ + tt) * HS_ + hs] = __float2bfloat16(v);
        } else {
          ((float*)p0)[(size_t)mg * N + ng] =
              res[(size_t)mg * N + ng] + v + bias[ng];
        }
      }
    }
}

// ---------------- 256^2 GEMM, BK=32, 8 waves, triple-buffered (96KB LDS,
// 1 block/CU), same single-barrier counted-vmcnt ledger. EPI: relu(C+bias) bf16.
__global__ __launch_bounds__(512, 2) void gemm_bt_256(
    const __hip_bfloat16* __restrict__ A, const __hip_bfloat16* __restrict__ Bt,
    int M, int N, int K,
    __hip_bfloat16* __restrict__ p0, const float* __restrict__ bias) {
  __shared__ short sA[3][256 * 32], sB[3][256 * 32];
  const int gdx = gridDim.x;           // N/256
  const int gdy = gridDim.y;           // M/256 (multiple of 8)
  const int orig = blockIdx.y * gdx + blockIdx.x;
  const int xcd = orig & 7;
  const int c = orig >> 3;
  const int rowsPerXcd = gdy >> 3;
  const int g = c / (2 * gdx);
  const int r = c % (2 * gdx);
  const int i2 = r & 1, nn = r >> 1;
  const int m0 = (xcd * rowsPerXcd + g * 2 + i2) * 256;
  const int n0 = nn * 256;
  const int t = threadIdx.x, l = t & 63, wid = t >> 6;
  const int wm = wid >> 2, wn = wid & 3, lg = l >> 4, lo = l & 15;
  f4v acc[8][4];
#pragma unroll
  for (int m = 0; m < 8; ++m)
#pragma unroll
    for (int n = 0; n < 4; ++n) acc[m][n] = (f4v){0.f, 0.f, 0.f, 0.f};
  const int NT = K >> 5;
  auto stage = [&](int kt, int bi) {
#pragma unroll
    for (int j = 0; j < 2; ++j) {
      int i = j * 512 + t;
      int row = i >> 2, sl = i & 3;
      int ss = sl ^ ((row >> 1) & 3);
      gll16(A + (size_t)(m0 + row) * K + kt * 32 + ss * 8, (char*)sA[bi] + i * 16);
      gll16(Bt + (size_t)(n0 + row) * K + kt * 32 + ss * 8, (char*)sB[bi] + i * 16);
    }
  };
  stage(0, 0);
  stage(1, 1);
  int bi = 0, bs = 2;
  for (int kt = 0; kt < NT; ++kt) {
    if (kt + 1 < NT) { VMCNT(4); } else { VMCNT(0); }
    BAR();
    const char* cA = (const char*)sA[bi];
    const char* cB = (const char*)sB[bi];
    s8v bf[4];
#pragma unroll
    for (int nr = 0; nr < 4; ++nr) {
      int row = wn * 64 + nr * 16 + lo;
      int ss = lg ^ ((row >> 1) & 3);
      bf[nr] = *(const s8v*)(cB + row * 64 + ss * 16);
    }
    {
      s8v af[4];
#pragma unroll
      for (int mr = 0; mr < 4; ++mr) {
        int row = wm * 128 + mr * 16 + lo;
        int ss = lg ^ ((row >> 1) & 3);
        af[mr] = *(const s8v*)(cA + row * 64 + ss * 16);
      }
      __builtin_amdgcn_s_setprio(1);
#pragma unroll
      for (int mr = 0; mr < 4; ++mr)
#pragma unroll
        for (int nr = 0; nr < 4; ++nr)
          acc[mr][nr] = __builtin_amdgcn_mfma_f32_16x16x32_bf16(af[mr], bf[nr], acc[mr][nr], 0, 0, 0);
      __builtin_amdgcn_s_setprio(0);
    }
    {
      s8v af[4];
#pragma unroll
      for (int mr = 0; mr < 4; ++mr) {
        int row = wm * 128 + (mr + 4) * 16 + lo;
        int ss = lg ^ ((row >> 1) & 3);
        af[mr] = *(const s8v*)(cA + row * 64 + ss * 16);
      }
      __builtin_amdgcn_s_setprio(1);
#pragma unroll
      for (int mr = 0; mr < 4; ++mr)
#pragma unroll
        for (int nr = 0; nr < 4; ++nr)
          acc[mr + 4][nr] = __builtin_amdgcn_mfma_f32_16x16x32_bf16(af[mr], bf[nr], acc[mr + 4][nr], 0, 0, 0);
      __builtin_amdgcn_s_setprio(0);
    }
    if (kt + 2 < NT) stage(kt + 2, bs);
    bi = (bi == 2) ? 0 : bi + 1;
    bs = (bs == 2) ? 0 : bs + 1;
  }
  // epilogue
#pragma unroll
  for (int mi = 0; mi < 8; ++mi)
#pragma unroll
    for (int j = 0; j < 4; ++j) {
      int mg = m0 + wm * 128 + mi * 16 + lg * 4 + j;
#pragma unroll
      for (int ni = 0; ni < 4; ++ni) {
        int ng = n0 + wn * 64 + ni * 16 + lo;
        float y = acc[mi][ni][j] + bias[ng];
        y = y > 0.f ? y : 0.f;
        p0[(size_t)mg * N + ng] = __float2bfloat16(y);
      }
    }
}

// ---------------- causal flash attention (verified round-8 state)
template <bool MASK>
__device__ __forceinline__ void attn_step(
    int s0, int qrow, int lg, int lo,
    const short* __restrict__ sKb, const short* __restrict__ sVb,
    short* __restrict__ sPw,
    const s8v (&qf)[2][2], f4v (&acc)[2][4], float (&rsum)[2][4]) {
  s8v kf[4][2];
#pragma unroll
  for (int si = 0; si < 4; ++si) {
    int row = si * 16 + lo;
#pragma unroll
    for (int kc = 0; kc < 2; ++kc) {
      int slot = (kc * 4 + lg) ^ (row & 7);
      kf[si][kc] = *(const s8v*)((const char*)sKb + row * 128 + slot * 16);
    }
  }
  f4v sfr[2][4];
#pragma unroll
  for (int mi = 0; mi < 2; ++mi)
#pragma unroll
    for (int si = 0; si < 4; ++si) {
      sfr[mi][si] = (f4v){0.f, 0.f, 0.f, 0.f};
#pragma unroll
      for (int kc = 0; kc < 2; ++kc)
        sfr[mi][si] = __builtin_amdgcn_mfma_f32_16x16x32_bf16(
            qf[mi][kc], kf[si][kc], sfr[mi][si], 0, 0, 0);
    }
  const float c = 0.18033688f;  // 0.125 * log2(e)
  float p[2][4][4];
#pragma unroll
  for (int mi = 0; mi < 2; ++mi)
#pragma unroll
    for (int si = 0; si < 4; ++si)
#pragma unroll
      for (int j = 0; j < 4; ++j) {
        float vv = sfr[mi][si][j] * c;
        if (MASK) {
          int r = qrow + mi * 16 + lg * 4 + j;
          int s = s0 + si * 16 + lo;
          vv = (s <= r) ? vv : -3e38f;
        }
        float e = exp2f(vv);
        p[mi][si][j] = e;
        rsum[mi][j] += e;
      }
#pragma unroll
  for (int mi = 0; mi < 2; ++mi)
#pragma unroll
    for (int si = 0; si < 4; ++si)
#pragma unroll
      for (int j = 0; j < 4; ++j) {
        int row = mi * 16 + lg * 4 + j;
        int s = si * 16 + lo;
        int slot = (s >> 3) ^ (row & 7);
        *(short*)((char*)sPw + row * 128 + slot * 16 + (s & 7) * 2) =
            f2b(p[mi][si][j]);
      }
  s8v pa[2][2], vf[4][2];
#pragma unroll
  for (int mi = 0; mi < 2; ++mi) {
    int row = mi * 16 + lo;
#pragma unroll
    for (int sb = 0; sb < 2; ++sb) {
      int slot = (sb * 4 + lg) ^ (row & 7);
      pa[mi][sb] = *(const s8v*)((const char*)sPw + row * 128 + slot * 16);
    }
  }
#pragma unroll
  for (int ni = 0; ni < 4; ++ni) {
    int row = ni * 16 + lo;
#pragma unroll
    for (int sb = 0; sb < 2; ++sb) {
      int slot = (sb * 4 + lg) ^ (row & 7);
      vf[ni][sb] = *(const s8v*)((const char*)sVb + row * 128 + slot * 16);
    }
  }
#pragma unroll
  for (int mi = 0; mi < 2; ++mi)
#pragma unroll
    for (int ni = 0; ni < 4; ++ni)
#pragma unroll
      for (int sb = 0; sb < 2; ++sb)
        acc[mi][ni] = __builtin_amdgcn_mfma_f32_16x16x32_bf16(
            pa[mi][sb], vf[ni][sb], acc[mi][ni], 0, 0, 0);
}

__global__ __launch_bounds__(256) void attn_kernel(
    const __hip_bfloat16* __restrict__ Q, const __hip_bfloat16* __restrict__ K,
    const __hip_bfloat16* __restrict__ Vt, __hip_bfloat16* __restrict__ O) {
  const int bh = blockIdx.y;
  const int t = threadIdx.x, w = t >> 6, l = t & 63, lg = l >> 4, lo = l & 15;
  const size_t kbase = (size_t)bh * T_ * HS_;
  const size_t vbase = (size_t)bh * HS_ * T_;
  __shared__ short sK[2][64 * 64];
  __shared__ short sV[2][64 * 64];
  __shared__ short sP[4][32 * 64];
  const int b = bh >> 4, hh = bh & 15;
  for (int pass = 0; pass < 2; ++pass) {
    const int tile = pass ? (15 - (int)blockIdx.x) : (int)blockIdx.x;
    const int q0 = tile * 128;
    const int qrow = q0 + w * 32;
    s8v qf[2][2];
#pragma unroll
    for (int mi = 0; mi < 2; ++mi)
#pragma unroll
      for (int kc = 0; kc < 2; ++kc)
        qf[mi][kc] = *(const s8v*)(Q + kbase +
                                   (size_t)(qrow + mi * 16 + lo) * HS_ +
                                   kc * 32 + lg * 8);
    f4v acc[2][4];
    float rsum[2][4];
#pragma unroll
    for (int mi = 0; mi < 2; ++mi) {
#pragma unroll
      for (int ni = 0; ni < 4; ++ni) acc[mi][ni] = (f4v){0.f, 0.f, 0.f, 0.f};
#pragma unroll
      for (int j = 0; j < 4; ++j) rsum[mi][j] = 0.f;
    }
    const int nst = q0 / 64 + 2;
    auto stg = [&](int st) {
      int bi = st & 1;
      int s0 = st * 64;
#pragma unroll
      for (int r = 0; r < 2; ++r) {
        int i = r * 256 + t;
        int row = i >> 3, sl = i & 7;
        int sls = sl ^ (row & 7);
        gll16(K + kbase + (size_t)(s0 + row) * HS_ + sls * 8,
              (char*)sK[bi] + i * 16);
        gll16(Vt + vbase + (size_t)row * T_ + s0 + sls * 8,
              (char*)sV[bi] + i * 16);
      }
    };
    stg(0);
    __syncthreads();
    for (int st = 0; st < nst; ++st) {
      if (st + 1 < nst) stg(st + 1);
      const int s0 = st * 64;
      if (s0 <= qrow + 31) {
        if (st < nst - 2)
          attn_step<false>(s0, qrow, lg, lo, sK[st & 1], sV[st & 1], sP[w],
                           qf, acc, rsum);
        else
          attn_step<true>(s0, qrow, lg, lo, sK[st & 1], sV[st & 1], sP[w],
                          qf, acc, rsum);
      }
      __syncthreads();
    }
#pragma unroll
    for (int mi = 0; mi < 2; ++mi)
#pragma unroll
      for (int j = 0; j < 4; ++j) {
        float rs = rsum[mi][j];
#pragma unroll
        for (int o = 1; o < 16; o <<= 1) rs += __shfl_xor(rs, o);
        int r = qrow + mi * 16 + lg * 4 + j;
        float inv = 1.f / rs;
#pragma unroll
        for (int ni = 0; ni < 4; ++ni) {
          int cc = ni * 16 + lo;
          O[((size_t)b * T_ + r) * D_ + hh * HS_ + cc] =
              __float2bfloat16(acc[mi][ni][j] * inv);
        }
      }
  }
}

extern "C" void kernel_launch(void* const* d_in, const int* in_sizes, int n_in,
                              void* d_out, int out_size, void* d_ws, size_t ws_size,
                              hipStream_t stream) {
  const float* x   = (const float*)d_in[0];
  const float* wq  = (const float*)d_in[1];
  const float* wk  = (const float*)d_in[2];
  const float* wv  = (const float*)d_in[3];
  const float* wo  = (const float*)d_in[4];
  const float* bo  = (const float*)d_in[5];
  const float* w1  = (const float*)d_in[6];
  const float* b1  = (const float*)d_in[7];
  const float* w2  = (const float*)d_in[8];
  const float* b2  = (const float*)d_in[9];
  const float* g1  = (const float*)d_in[10];
  const float* be1 = (const float*)d_in[11];
  const float* g2  = (const float*)d_in[12];
  const float* be2 = (const float*)d_in[13];
  float* out = (float*)d_out;

  char* ws = (char*)d_ws;
  auto alloc = [&](size_t bytes) {
    char* p = ws;
    ws += (bytes + 255) & ~(size_t)255;
    return p;
  };
  __hip_bfloat16* qkvT  = (__hip_bfloat16*)alloc((size_t)3 * D_ * D_ * 2);
  __hip_bfloat16* woT   = (__hip_bfloat16*)alloc((size_t)D_ * D_ * 2);
  __hip_bfloat16* w1T   = (__hip_bfloat16*)alloc((size_t)DFF_ * D_ * 2);
  __hip_bfloat16* w2T   = (__hip_bfloat16*)alloc((size_t)D_ * DFF_ * 2);
  __hip_bfloat16* hbuf  = (__hip_bfloat16*)alloc((size_t)M_TOT * D_ * 2);
  float*          x1    = (float*)alloc((size_t)M_TOT * D_ * 4);
  __hip_bfloat16* Vtb   = (__hip_bfloat16*)x1;   // disjoint live ranges
  char* aliased = alloc((size_t)M_TOT * DFF_ * 2);
  __hip_bfloat16* Qb    = (__hip_bfloat16*)(aliased);
  __hip_bfloat16* Kb    = (__hip_bfloat16*)(aliased + (size_t)M_TOT * D_ * 2);
  __hip_bfloat16* Vb    = (__hip_bfloat16*)(aliased + (size_t)M_TOT * D_ * 4);
  __hip_bfloat16* attnb = (__hip_bfloat16*)(aliased + (size_t)M_TOT * D_ * 6);
  __hip_bfloat16* ffb   = (__hip_bfloat16*)(aliased);

  transpose_all_kernel<<<dim3(12288), dim3(32, 8), 0, stream>>>(
      wq, wk, wv, wo, w1, w2, qkvT, woT, w1T, w2T);
  ln_kernel<<<M_TOT, 256, 0, stream>>>(x, g1, be1, hbuf);
  // QKV (128^2, scatter epilogue)
  gemm_bt_128<0><<<dim3(24, 64), 256, 0, stream>>>(hbuf, qkvT, M_TOT, 3 * D_, D_,
                                                   Qb, Kb, Vb, nullptr, nullptr);
  transpose_v_kernel<<<dim3(32, 64), 256, 0, stream>>>(Vb, Vtb);
  attn_kernel<<<dim3(8, 64), 256, 0, stream>>>(Qb, Kb, Vtb, attnb);
  // out proj + residual (128^2)
  gemm_bt_128<1><<<dim3(8, 64), 256, 0, stream>>>(attnb, woT, M_TOT, D_, D_,
                                                  x1, nullptr, nullptr, bo, x);
  ln_kernel<<<M_TOT, 256, 0, stream>>>(x1, g2, be2, hbuf);
  // FFN1 relu (256^2, triple-buffered)
  gemm_bt_256<<<dim3(16, 32), 512, 0, stream>>>(hbuf, w1T, M_TOT, DFF_, D_,
                                                ffb, b1);
  // FFN2 + residual -> out (128^2)
  gemm_bt_128<1><<<dim3(8, 64), 256, 0, stream>>>(ffb, w2T, M_TOT, D_, DFF_,
                                                  out, nullptr, nullptr, b2, x1);
}